// Round 1
// baseline (1128.989 us; speedup 1.0000x reference)
//
#include <hip/hip_runtime.h>
#include <math.h>

typedef _Float16 half8 __attribute__((ext_vector_type(8)));
typedef float floatx4 __attribute__((ext_vector_type(4)));

#define TILE_M 64
#define TILE_N 64
#define TILE_K 32
#define LDS_PITCH 40  // TILE_K + 8 halfs = 80B rows: keeps 16B alignment, breaks pow-2 bank stride

// Generic C = alpha * A @ B, f16 MFMA, fp32 in/out.
// A[m][k] = A[m*lda_m + k*lda_k] (one of lda_m/lda_k must be 1)
// B[k][n] = B[k*ldb_k + n]
// C store col remap: cmap ? col -> (col>>6)*128 + (col&63) : col   (head interleave)
// batching: z -> (zb = z/nh, zh = z%nh), pointer offsets per (zb, zh)
__global__ __launch_bounds__(256) void gemm_f16_kernel(
    const float* __restrict__ A, const float* __restrict__ B, float* __restrict__ C,
    int M, int N, int K,
    long lda_m, long lda_k, long ldb_k, long ldc,
    int cmap, float alpha, int nh,
    long aoff_b, long aoff_h, long boff_b, long boff_h, long coff_b, long coff_h)
{
    __shared__ __align__(16) _Float16 As[TILE_M][LDS_PITCH];
    __shared__ __align__(16) _Float16 Bs[TILE_N][LDS_PITCH];

    const int z = blockIdx.z;
    const int zb = z / nh, zh = z % nh;
    const float* Ab = A + (long)zb * aoff_b + (long)zh * aoff_h;
    const float* Bb = B + (long)zb * boff_b + (long)zh * boff_h;
    float* Cb = C + (long)zb * coff_b + (long)zh * coff_h;

    const int m0 = blockIdx.y * TILE_M;
    const int n0 = blockIdx.x * TILE_N;
    const int t = threadIdx.x;
    const int wave = t >> 6, lane = t & 63;
    const int lr = lane & 15, lq = lane >> 4;
    const int wm = (wave & 1) * 32, wn = (wave >> 1) * 32;

    const int sm = t >> 2;        // staging row (0..63)
    const int sk = (t & 3) * 8;   // staging k-chunk base {0,8,16,24}

    floatx4 acc00 = {0.f,0.f,0.f,0.f}, acc01 = {0.f,0.f,0.f,0.f};
    floatx4 acc10 = {0.f,0.f,0.f,0.f}, acc11 = {0.f,0.f,0.f,0.f};

    for (int k0 = 0; k0 < K; k0 += TILE_K) {
        // ---- stage A tile: As[m][k] ----
        {
            half8 av;
            if (lda_k == 1) {
                const float* ap = Ab + (long)(m0 + sm) * lda_m + (k0 + sk);
                #pragma unroll
                for (int i = 0; i < 8; ++i) av[i] = (_Float16)ap[i];
            } else {  // lda_m == 1 (transposed access, coalesced along m)
                const float* ap = Ab + (long)(m0 + sm) + (long)(k0 + sk) * lda_k;
                #pragma unroll
                for (int i = 0; i < 8; ++i) av[i] = (_Float16)ap[(long)i * lda_k];
            }
            *(half8*)&As[sm][sk] = av;
        }
        // ---- stage B tile transposed: Bs[n][k] ----
        {
            half8 bv;
            const float* bp = Bb + (long)(k0 + sk) * ldb_k + (n0 + sm);
            #pragma unroll
            for (int i = 0; i < 8; ++i) bv[i] = (_Float16)bp[(long)i * ldb_k];
            *(half8*)&Bs[sm][sk] = bv;
        }
        __syncthreads();

        // fragments: A[m=lane&15][k=lq*8+j], B[k=lq*8+j][n=lane&15]
        half8 a0 = *(const half8*)&As[wm + lr][lq * 8];
        half8 a1 = *(const half8*)&As[wm + 16 + lr][lq * 8];
        half8 b0 = *(const half8*)&Bs[wn + lr][lq * 8];
        half8 b1 = *(const half8*)&Bs[wn + 16 + lr][lq * 8];
        acc00 = __builtin_amdgcn_mfma_f32_16x16x32_f16(a0, b0, acc00, 0, 0, 0);
        acc01 = __builtin_amdgcn_mfma_f32_16x16x32_f16(a0, b1, acc01, 0, 0, 0);
        acc10 = __builtin_amdgcn_mfma_f32_16x16x32_f16(a1, b0, acc10, 0, 0, 0);
        acc11 = __builtin_amdgcn_mfma_f32_16x16x32_f16(a1, b1, acc11, 0, 0, 0);
        __syncthreads();
    }

    // C/D layout: col = lane&15, row = (lane>>4)*4 + reg
    #pragma unroll
    for (int r = 0; r < 4; ++r) {
        int row0 = m0 + wm + lq * 4 + r;
        int row1 = row0 + 16;
        int colA = n0 + wn + lr;
        int colB = colA + 16;
        int cA = cmap ? ((colA >> 6) * 128 + (colA & 63)) : colA;
        int cB = cmap ? ((colB >> 6) * 128 + (colB & 63)) : colB;
        Cb[(long)row0 * ldc + cA] = alpha * acc00[r];
        Cb[(long)row0 * ldc + cB] = alpha * acc01[r];
        Cb[(long)row1 * ldc + cA] = alpha * acc10[r];
        Cb[(long)row1 * ldc + cB] = alpha * acc11[r];
    }
}

// rope: half_dim=32 rotates (16+16 rotate-half), dims 32..63 pass through.
// inv_freq[j] = 10000^-(2j/32), ang = (s/40) * inv_freq[d&15]
__global__ void rope_k_kernel(const float* __restrict__ kr,
                              float* __restrict__ krope_out,
                              float* __restrict__ k_flat)
{
    int idx = blockIdx.x * 256 + threadIdx.x;   // 4096*1024 exact
    int bs = idx >> 10;
    int c = idx & 1023;
    int h = c >> 6, d = c & 63;
    int s = bs & 2047;
    float x = kr[idx];
    float y = x;
    if (d < 32) {
        int j = d & 15;
        float invf = 1.0f / powf(10000.0f, (float)(2 * j) / 32.0f);
        float ang = ((float)s / 40.0f) * invf;
        float cv = cosf(ang), sv = sinf(ang);
        float other = (d < 16) ? -kr[idx + 16] : kr[idx - 16];
        y = x * cv + other * sv;
    }
    krope_out[idx] = y;                                   // output 2
    k_flat[(long)bs * 2048 + h * 128 + 64 + d] = y;       // rope half of k_flat
}

__global__ void rope_q_kernel(const float* __restrict__ qr,
                              const float* __restrict__ qc,
                              float* __restrict__ q_flat)
{
    int idx = blockIdx.x * 256 + threadIdx.x;   // 4096*2048 exact
    int bs = idx >> 11;
    int c = idx & 2047;
    int h = c >> 7, d = c & 127;
    float y;
    if (d < 64) {
        y = qc[(long)bs * 1024 + h * 64 + d];             // content half
    } else {
        int dd = d - 64;
        long base = (long)bs * 1024 + h * 64;
        float x = qr[base + dd];
        y = x;
        if (dd < 32) {
            int s = bs & 2047;
            int j = dd & 15;
            float invf = 1.0f / powf(10000.0f, (float)(2 * j) / 32.0f);
            float ang = ((float)s / 40.0f) * invf;
            float cv = cosf(ang), sv = sinf(ang);
            float other = (dd < 16) ? -qr[base + dd + 16] : qr[base + dd - 16];
            y = x * cv + other * sv;
        }
    }
    q_flat[idx] = y;
}

extern "C" void kernel_launch(void* const* d_in, const int* in_sizes, int n_in,
                              void* d_out, int out_size, void* d_ws, size_t ws_size,
                              hipStream_t stream)
{
    const float* x     = (const float*)d_in[0];
    const float* W_dkv = (const float*)d_in[1];
    const float* W_dq  = (const float*)d_in[2];
    const float* W_uk  = (const float*)d_in[3];
    const float* W_uv  = (const float*)d_in[4];
    const float* W_uq  = (const float*)d_in[5];
    const float* W_kr  = (const float*)d_in[6];
    const float* W_qr  = (const float*)d_in[7];
    const float* W_out = (const float*)d_in[8];

    // outputs concatenated: output (2*2048*2048) | c_kv (2*2048*1024) | k_rope (2*2048*1024)
    float* out_main  = (float*)d_out;
    float* out_ckv   = out_main + 8388608;
    float* out_krope = out_ckv + 4194304;

    float* ws       = (float*)d_ws;
    float* c_q_buf  = ws;                   // 4.19M (dead after step 4 -> reused as Mbuf)
    float* q_c_buf  = ws + 4194304;         // 4.19M (dead after rope_q)
    float* k_r_buf  = ws + 8388608;         // 4.19M (dead after rope_k -> reused as Pbuf)
    float* q_r_buf  = ws + 12582912;        // 4.19M (dead after rope_q -> inside Pbuf)
    float* k_flat   = ws + 16777216;        // 8.39M  (bs, h*128+d)
    float* q_flat   = ws + 25165824;        // 8.39M
    float* v_flat   = ws + 33554432;        // 8.39M   -> total 41,943,040 floats (168 MB)
    float* Mbuf     = ws;                   // 32*128*128 = 524288  (aliases dead c_q_buf)
    float* Pbuf     = ws + 8388608;         // 2*2048*2048 = 8.39M  (aliases dead k_r/q_r)

    #define G(A_,B_,C_,M_,N_,K_, lam, lak, lbk, ldc_, cmap_, alpha_, nz_, nh_, ab,ah,bb,bh,cb,ch) \
        hipLaunchKernelGGL(gemm_f16_kernel, dim3((N_)/64,(M_)/64,(nz_)), dim3(256), 0, stream, \
            A_, B_, C_, M_, N_, K_, (long)(lam),(long)(lak),(long)(lbk),(long)(ldc_), cmap_, alpha_, nh_, \
            (long)(ab),(long)(ah),(long)(bb),(long)(bh),(long)(cb),(long)(ch))

    // 1. c_kv = x @ W_dkv  (also output 1)
    G(x, W_dkv, out_ckv, 4096, 1024, 2048, 2048, 1, 1024, 1024, 0, 1.0f, 1, 1, 0,0,0,0,0,0);
    // 2. c_q = x @ W_dq
    G(x, W_dq, c_q_buf, 4096, 1024, 2048, 2048, 1, 1024, 1024, 0, 1.0f, 1, 1, 0,0,0,0,0,0);
    // 3. k_r_pre = x @ W_kr
    G(x, W_kr, k_r_buf, 4096, 1024, 2048, 2048, 1, 1024, 1024, 0, 1.0f, 1, 1, 0,0,0,0,0,0);
    // 4. q_c = c_q @ W_uq
    G(c_q_buf, W_uq, q_c_buf, 4096, 1024, 1024, 1024, 1, 1024, 1024, 0, 1.0f, 1, 1, 0,0,0,0,0,0);
    // 5. k_c = c_kv @ W_uk  -> k_flat content halves (col remap h*64+d -> h*128+d)
    G(out_ckv, W_uk, k_flat, 4096, 1024, 1024, 1024, 1, 1024, 2048, 1, 1.0f, 1, 1, 0,0,0,0,0,0);
    // 6. v_flat = c_kv @ W_uv
    G(out_ckv, W_uv, v_flat, 4096, 2048, 1024, 1024, 1, 2048, 2048, 0, 1.0f, 1, 1, 0,0,0,0,0,0);
    // 7. q_r_pre = q_c @ W_qr
    G(q_c_buf, W_qr, q_r_buf, 4096, 1024, 1024, 1024, 1, 1024, 1024, 0, 1.0f, 1, 1, 0,0,0,0,0,0);
    // 8/9. rope + interleave (k_rope is output 2)
    hipLaunchKernelGGL(rope_k_kernel, dim3(16384), dim3(256), 0, stream, k_r_buf, out_krope, k_flat);
    hipLaunchKernelGGL(rope_q_kernel, dim3(32768), dim3(256), 0, stream, q_r_buf, q_c_buf, q_flat);
    // 10. M[b,h] = (1/sqrt(128)) * q_h^T @ v_h   (A transposed: lda_m=1, lda_k=2048)
    G(q_flat, v_flat, Mbuf, 128, 128, 2048, 1, 2048, 2048, 128, 0, 0.08838834764831845f,
      32, 16, 4194304, 128, 4194304, 128, 262144, 16384);
    // 11. P[b,h] = M[b,h] @ W_out_h
    G(Mbuf, W_out, Pbuf, 128, 2048, 128, 128, 1, 2048, 2048, 0, 1.0f,
      32, 16, 262144, 16384, 0, 262144, 4194304, 262144);
    // 12. output[b] = k_flat[b] @ P[b]
    G(k_flat, Pbuf, out_main, 2048, 2048, 2048, 2048, 1, 2048, 2048, 0, 1.0f,
      2, 1, 4194304, 0, 4194304, 0, 4194304, 0);

    #undef G
}

// Round 2
// 629.125 us; speedup vs baseline: 1.7945x; 1.7945x over previous
//
#include <hip/hip_runtime.h>
#include <math.h>

typedef _Float16 half8 __attribute__((ext_vector_type(8)));
typedef float floatx4 __attribute__((ext_vector_type(4)));

typedef const uint32_t __attribute__((address_space(1)))* gp1_t;
typedef uint32_t __attribute__((address_space(3)))* lp3_t;
#define GLDS16(g, l) __builtin_amdgcn_global_load_lds((gp1_t)(const void*)(g), (lp3_t)(void*)(l), 16, 0, 0)

#define BK 32

// C[m][n] = alpha * sum_k A[m][k] * B[n][k]; A,B f16 k-contiguous; tile 128x128.
// m97 structure: global_load_lds width-16 staging, 2-barrier K-loop, 16x16x32 f16 MFMA.
__global__ __launch_bounds__(256) void gemm_fast(
    const _Float16* __restrict__ A, const _Float16* __restrict__ B,
    float* __restrict__ Cf, _Float16* __restrict__ Ch,
    int K, long lda, long ldb, long ldcf, long ldch,
    int cmap, float alpha, int nh,
    long aoff_b, long aoff_h, long boff_b, long boff_h, long coff_b, long coff_h)
{
    __shared__ __align__(16) _Float16 As[128 * BK];
    __shared__ __align__(16) _Float16 Bs[128 * BK];

    const int z = blockIdx.z;
    const int zb = (nh == 1) ? z : z / nh;
    const int zh = (nh == 1) ? 0 : z % nh;
    const _Float16* Ab = A + (long)zb * aoff_b + (long)zh * aoff_h;
    const _Float16* Bb = B + (long)zb * boff_b + (long)zh * boff_h;
    const long cofs = (long)zb * coff_b + (long)zh * coff_h;

    const long m0 = (long)blockIdx.y * 128;
    const long n0 = (long)blockIdx.x * 128;
    const int t = threadIdx.x;
    const int wave = t >> 6, lane = t & 63;
    const int lr = lane & 15, lq = lane >> 4;
    const int wm = (wave & 1) * 64, wn = (wave >> 1) * 64;

    // staging chunk c (16B = 8 halfs): row = c>>2, k-chunk = (c&3)*8; c = i*256 + wave*64 + lane
    const int c0 = wave * 64 + lane;
    const int c1 = c0 + 256;
    const _Float16* ga0 = Ab + (m0 + (c0 >> 2)) * lda + (c0 & 3) * 8;
    const _Float16* ga1 = Ab + (m0 + (c1 >> 2)) * lda + (c1 & 3) * 8;
    const _Float16* gb0 = Bb + (n0 + (c0 >> 2)) * ldb + (c0 & 3) * 8;
    const _Float16* gb1 = Bb + (n0 + (c1 >> 2)) * ldb + (c1 & 3) * 8;
    // wave-uniform LDS bases (HW adds lane*16B)
    _Float16* lA0 = As + wave * 512;
    _Float16* lA1 = As + 2048 + wave * 512;
    _Float16* lB0 = Bs + wave * 512;
    _Float16* lB1 = Bs + 2048 + wave * 512;

    floatx4 acc[4][4];
    #pragma unroll
    for (int i = 0; i < 4; ++i)
        #pragma unroll
        for (int j = 0; j < 4; ++j) acc[i][j] = (floatx4){0.f, 0.f, 0.f, 0.f};

    for (int k0 = 0; k0 < K; k0 += BK) {
        GLDS16(ga0, lA0); GLDS16(ga1, lA1);
        GLDS16(gb0, lB0); GLDS16(gb1, lB1);
        ga0 += BK; ga1 += BK; gb0 += BK; gb1 += BK;
        __syncthreads();

        half8 a[4], b[4];
        #pragma unroll
        for (int i = 0; i < 4; ++i) a[i] = *(const half8*)(As + (wm + i * 16 + lr) * BK + lq * 8);
        #pragma unroll
        for (int j = 0; j < 4; ++j) b[j] = *(const half8*)(Bs + (wn + j * 16 + lr) * BK + lq * 8);
        #pragma unroll
        for (int i = 0; i < 4; ++i)
            #pragma unroll
            for (int j = 0; j < 4; ++j)
                acc[i][j] = __builtin_amdgcn_mfma_f32_16x16x32_f16(a[i], b[j], acc[i][j], 0, 0, 0);
        __syncthreads();
    }

    // C/D layout: col = lane&15, row = (lane>>4)*4 + reg
    #pragma unroll
    for (int i = 0; i < 4; ++i)
        #pragma unroll
        for (int j = 0; j < 4; ++j)
            #pragma unroll
            for (int r = 0; r < 4; ++r) {
                long row = m0 + wm + i * 16 + lq * 4 + r;
                long col = n0 + wn + j * 16 + lr;
                long cm = cmap ? ((col >> 6) * 128 + (col & 63)) : col;
                float v = alpha * acc[i][j][r];
                if (Cf) Cf[cofs + row * ldcf + cm] = v;
                if (Ch) Ch[cofs + row * ldch + cm] = (_Float16)v;
            }
}

__global__ void cast_f16_kernel(const float* __restrict__ in, _Float16* __restrict__ out, int n)
{
    int i = blockIdx.x * 256 + threadIdx.x;
    if (i < n) out[i] = (_Float16)in[i];
}

// out[c][r] = (f16) in[r][c]
__global__ void transpose_f16_kernel(const float* __restrict__ in, _Float16* __restrict__ out,
                                     int R, int C)
{
    __shared__ float tbuf[32][33];
    int c0 = blockIdx.x * 32, r0 = blockIdx.y * 32;
    for (int i = threadIdx.y; i < 32; i += 8)
        tbuf[i][threadIdx.x] = in[(long)(r0 + i) * C + c0 + threadIdx.x];
    __syncthreads();
    for (int i = threadIdx.y; i < 32; i += 8)
        out[(long)(c0 + i) * R + r0 + threadIdx.x] = (_Float16)tbuf[threadIdx.x][i];
}

// rope on k_r (natural layout [bs][h*64+d]); writes fp32 output 2 and f16 rope half of k_flat
__global__ void rope_k_kernel(const float* __restrict__ kr,
                              float* __restrict__ krope_out,
                              _Float16* __restrict__ k_flat)
{
    int idx = blockIdx.x * 256 + threadIdx.x;   // 4096*1024
    int bs = idx >> 10;
    int c = idx & 1023;
    int h = c >> 6, d = c & 63;
    float x = kr[idx];
    float y = x;
    if (d < 32) {
        int s = bs & 2047;
        int j = d & 15;
        float invf = powf(10000.0f, -(float)j / 16.0f);
        float ang = ((float)s / 40.0f) * invf;
        float other = (d < 16) ? -kr[idx + 16] : kr[idx - 16];
        y = x * cosf(ang) + other * sinf(ang);
    }
    krope_out[idx] = y;
    k_flat[(long)bs * 2048 + h * 128 + 64 + d] = (_Float16)y;
}

// build qT [2048 dims][4096 seq] f16 from q_cT (f16 [1024][4096]) and q_rT (fp32 [1024][4096])
__global__ void rope_qT_kernel(const _Float16* __restrict__ q_cT,
                               const float* __restrict__ q_rT,
                               _Float16* __restrict__ qT)
{
    long idx = (long)blockIdx.x * 256 + threadIdx.x;   // 2048*4096
    int row = (int)(idx >> 12);
    int col = (int)(idx & 4095);
    int h = row >> 7, d = row & 127;
    if (d < 64) {
        qT[idx] = q_cT[(long)(h * 64 + d) * 4096 + col];
    } else {
        int dd = d - 64;
        long base = (long)(h * 64) * 4096 + col;
        float x = q_rT[base + (long)dd * 4096];
        float y = x;
        if (dd < 32) {
            int s = col & 2047;
            int j = dd & 15;
            float invf = powf(10000.0f, -(float)j / 16.0f);
            float ang = ((float)s / 40.0f) * invf;
            float other = (dd < 16) ? -q_rT[base + (long)(dd + 16) * 4096]
                                    :  q_rT[base + (long)(dd - 16) * 4096];
            y = x * cosf(ang) + other * sinf(ang);
        }
        qT[idx] = (_Float16)y;
    }
}

extern "C" void kernel_launch(void* const* d_in, const int* in_sizes, int n_in,
                              void* d_out, int out_size, void* d_ws, size_t ws_size,
                              hipStream_t stream)
{
    const float* x     = (const float*)d_in[0];
    const float* W_dkv = (const float*)d_in[1];
    const float* W_dq  = (const float*)d_in[2];
    const float* W_uk  = (const float*)d_in[3];
    const float* W_uv  = (const float*)d_in[4];
    const float* W_uq  = (const float*)d_in[5];
    const float* W_kr  = (const float*)d_in[6];
    const float* W_qr  = (const float*)d_in[7];
    const float* W_out = (const float*)d_in[8];

    float* out_main  = (float*)d_out;            // 2*2048*2048
    float* out_ckv   = out_main + 8388608;       // 2*2048*1024
    float* out_krope = out_ckv + 4194304;        // 2*2048*1024

    char* w = (char*)d_ws;
    size_t off = 0;
    auto alloc = [&](size_t bytes) { void* p = w + off; off += (bytes + 255) & ~(size_t)255; return p; };

    // overlaid regions (lifetime-disjoint)
    void* reg0 = alloc(16777216);   // xh (f16 8.4M)        -> qT (f16 8.4M)
    void* reg1 = alloc(16777216);   // k_r (fp32 4.2M)      -> PT (f16 8.4M)
    void* reg2 = alloc(16777216);   // q_rT (fp32 4.2M)     -> Mbuf (f16 0.5M)
    _Float16* xh    = (_Float16*)reg0;  _Float16* qT   = (_Float16*)reg0;
    float*    k_r   = (float*)reg1;     _Float16* PT   = (_Float16*)reg1;
    float*    q_rT  = (float*)reg2;     _Float16* Mbuf = (_Float16*)reg2;

    _Float16* c_kv_h = (_Float16*)alloc(8388608);
    _Float16* c_q_h  = (_Float16*)alloc(8388608);
    _Float16* WdkvT  = (_Float16*)alloc(4194304);
    _Float16* WdqT   = (_Float16*)alloc(4194304);
    _Float16* WkrT   = (_Float16*)alloc(4194304);
    _Float16* WukT   = (_Float16*)alloc(2097152);
    _Float16* WuqT   = (_Float16*)alloc(2097152);
    _Float16* Wuqh   = (_Float16*)alloc(2097152);
    _Float16* WuvT   = (_Float16*)alloc(4194304);
    _Float16* WqrT   = (_Float16*)alloc(2097152);
    _Float16* WuqrT  = (_Float16*)alloc(2097152);
    _Float16* WoutT  = (_Float16*)alloc(8388608);
    _Float16* k_flat = (_Float16*)alloc(16777216);  // [4096][2048]
    _Float16* vT     = (_Float16*)alloc(16777216);  // [2048][4096]
    _Float16* q_cT   = (_Float16*)alloc(8388608);   // [1024][4096]

    #define CAST(in_, out_, n_) \
        hipLaunchKernelGGL(cast_f16_kernel, dim3((n_) / 256), dim3(256), 0, stream, in_, out_, n_)
    #define TR(in_, out_, R_, C_) \
        hipLaunchKernelGGL(transpose_f16_kernel, dim3((C_) / 32, (R_) / 32), dim3(32, 8), 0, stream, in_, out_, R_, C_)
    #define GF(A_,B_,Cf_,Ch_,M_,N_,K_,lda_,ldb_,ldcf_,ldch_,cmap_,alpha_,nz_,nh_,ab,ah,bb,bh,cb,ch2) \
        hipLaunchKernelGGL(gemm_fast, dim3((N_)/128,(M_)/128,(nz_)), dim3(256), 0, stream, \
            A_, B_, Cf_, Ch_, (int)(K_), (long)(lda_), (long)(ldb_), (long)(ldcf_), (long)(ldch_), \
            cmap_, (float)(alpha_), nh_, (long)(ab),(long)(ah),(long)(bb),(long)(bh),(long)(cb),(long)(ch2))

    // --- prep: f16 casts + weight transposes ---
    CAST(x, xh, 8388608);
    CAST(W_uq, Wuqh, 1048576);
    TR(W_dkv, WdkvT, 2048, 1024);
    TR(W_dq,  WdqT,  2048, 1024);
    TR(W_kr,  WkrT,  2048, 1024);
    TR(W_uk,  WukT,  1024, 1024);
    TR(W_uq,  WuqT,  1024, 1024);
    TR(W_uv,  WuvT,  1024, 2048);
    TR(W_qr,  WqrT,  1024, 1024);
    TR(W_out, WoutT, 2048, 2048);

    // G1: c_kv = x @ W_dkv  (fp32 output 1 + f16 copy)
    GF(xh, WdkvT, out_ckv, c_kv_h, 4096, 1024, 2048, 2048, 2048, 1024, 1024, 0, 1.0, 1, 1, 0,0,0,0,0,0);
    // G2: c_q (f16)
    GF(xh, WdqT, (float*)nullptr, c_q_h, 4096, 1024, 2048, 2048, 2048, 0, 1024, 0, 1.0, 1, 1, 0,0,0,0,0,0);
    // G3: k_r = x @ W_kr (fp32)
    GF(xh, WkrT, k_r, (_Float16*)nullptr, 4096, 1024, 2048, 2048, 2048, 1024, 0, 0, 1.0, 1, 1, 0,0,0,0,0,0);
    // G4: W_uqr^T = (W_uq @ W_qr)^T  [r][cd]
    GF(WqrT, Wuqh, (float*)nullptr, WuqrT, 1024, 1024, 1024, 1024, 1024, 0, 1024, 0, 1.0, 1, 1, 0,0,0,0,0,0);
    // G5: k_c -> content halves of k_flat (col remap h*64+d -> h*128+d)
    GF(c_kv_h, WukT, (float*)nullptr, k_flat, 4096, 1024, 1024, 1024, 1024, 0, 2048, 1, 1.0, 1, 1, 0,0,0,0,0,0);
    // G6: vT[hdv][s] = W_uv^T @ c_kv
    GF(WuvT, c_kv_h, (float*)nullptr, vT, 2048, 4096, 1024, 1024, 1024, 0, 4096, 0, 1.0, 1, 1, 0,0,0,0,0,0);
    // G7: q_cT[uq][s]
    GF(WuqT, c_q_h, (float*)nullptr, q_cT, 1024, 4096, 1024, 1024, 1024, 0, 4096, 0, 1.0, 1, 1, 0,0,0,0,0,0);
    // G8: q_rT[r][s] (fp32, rope input)
    GF(WuqrT, c_q_h, q_rT, (_Float16*)nullptr, 1024, 4096, 1024, 1024, 1024, 4096, 0, 0, 1.0, 1, 1, 0,0,0,0,0,0);
    // rope
    hipLaunchKernelGGL(rope_k_kernel, dim3(16384), dim3(256), 0, stream, k_r, out_krope, k_flat);
    hipLaunchKernelGGL(rope_qT_kernel, dim3(32768), dim3(256), 0, stream, q_cT, q_rT, qT);
    // G9: M[b,h][dk][dv] = (1/sqrt(128)) qT_h @ vT_h^T  (K=seq)
    GF(qT, vT, (float*)nullptr, Mbuf, 128, 128, 2048, 4096, 4096, 0, 128, 0, 0.08838834764831845, 32, 16,
       2048, 524288, 2048, 524288, 262144, 16384);
    // G10: PT[b][o][h*128+dk] = W_out_h^T @ M^T per head
    GF(WoutT, Mbuf, (float*)nullptr, PT, 2048, 128, 128, 2048, 128, 0, 2048, 0, 1.0, 32, 16,
       0, 128, 262144, 16384, 4194304, 128);
    // G11: output[b] = k_flat[b] @ PT[b]^T (fp32 output 0)
    GF(k_flat, PT, out_main, (_Float16*)nullptr, 2048, 2048, 2048, 2048, 2048, 2048, 0, 0, 1.0, 2, 1,
       4194304, 0, 4194304, 0, 4194304, 0);

    #undef CAST
    #undef TR
    #undef GF
}

// Round 4
// 504.189 us; speedup vs baseline: 2.2392x; 1.2478x over previous
//
#include <hip/hip_runtime.h>
#include <math.h>

typedef _Float16 half8 __attribute__((ext_vector_type(8)));
typedef float floatx4 __attribute__((ext_vector_type(4)));

typedef const uint32_t __attribute__((address_space(1)))* gp1_t;
typedef uint32_t __attribute__((address_space(3)))* lp3_t;
#define GLDS16(g, l) __builtin_amdgcn_global_load_lds((gp1_t)(const void*)(g), (lp3_t)(void*)(l), 16, 0, 0)

#define BK 32

// C[m][n] = alpha * sum_k A[m][k]*B[n][k]; A,B f16 k-contiguous; 128x128 tile, m97 structure.
// Outputs: optional f16 Ch (full, with optional head-interleave col remap) and
// optional fp32 Cf restricted to col window [cf_lo, cf_hi).
// Batching: z -> (zb, zh, ks) with nh heads and nsk K-splits (Kc = K chunk per split);
// split-K partials go to Cf slice ks via coff_s (ELEMENT stride).
__global__ __launch_bounds__(256) void gemm_fast(
    const _Float16* __restrict__ A, const _Float16* __restrict__ B,
    float* __restrict__ Cf, _Float16* __restrict__ Ch,
    int Kc, long lda, long ldb, long ldcf, long ldch,
    int cmap, long cf_lo, long cf_hi, float alpha, int nh, int nsk,
    long aoff_b, long aoff_h, long boff_b, long boff_h,
    long coff_b, long coff_h, long coff_s)
{
    __shared__ __align__(16) _Float16 As[128 * BK];
    __shared__ __align__(16) _Float16 Bs[128 * BK];

    const int z = blockIdx.z;
    const int hs = nh * nsk;
    const int zb = z / hs;
    const int r0_ = z % hs;
    const int zh = r0_ / nsk;
    const int ks = r0_ % nsk;

    const _Float16* Ab = A + (long)zb * aoff_b + (long)zh * aoff_h + (long)ks * Kc;
    const _Float16* Bb = B + (long)zb * boff_b + (long)zh * boff_h + (long)ks * Kc;
    const long cofs = (long)zb * coff_b + (long)zh * coff_h + (long)ks * coff_s;

    const long m0 = (long)blockIdx.y * 128;
    const long n0 = (long)blockIdx.x * 128;
    const int t = threadIdx.x;
    const int wave = t >> 6, lane = t & 63;
    const int lr = lane & 15, lq = lane >> 4;
    const int wm = (wave & 1) * 64, wn = (wave >> 1) * 64;

    const int c0 = wave * 64 + lane;
    const int c1 = c0 + 256;
    const _Float16* ga0 = Ab + (m0 + (c0 >> 2)) * lda + (c0 & 3) * 8;
    const _Float16* ga1 = Ab + (m0 + (c1 >> 2)) * lda + (c1 & 3) * 8;
    const _Float16* gb0 = Bb + (n0 + (c0 >> 2)) * ldb + (c0 & 3) * 8;
    const _Float16* gb1 = Bb + (n0 + (c1 >> 2)) * ldb + (c1 & 3) * 8;
    _Float16* lA0 = As + wave * 512;
    _Float16* lA1 = As + 2048 + wave * 512;
    _Float16* lB0 = Bs + wave * 512;
    _Float16* lB1 = Bs + 2048 + wave * 512;

    floatx4 acc[4][4];
    #pragma unroll
    for (int i = 0; i < 4; ++i)
        #pragma unroll
        for (int j = 0; j < 4; ++j) acc[i][j] = (floatx4){0.f, 0.f, 0.f, 0.f};

    for (int k0 = 0; k0 < Kc; k0 += BK) {
        GLDS16(ga0, lA0); GLDS16(ga1, lA1);
        GLDS16(gb0, lB0); GLDS16(gb1, lB1);
        ga0 += BK; ga1 += BK; gb0 += BK; gb1 += BK;
        __syncthreads();

        half8 a[4], b[4];
        #pragma unroll
        for (int i = 0; i < 4; ++i) a[i] = *(const half8*)(As + (wm + i * 16 + lr) * BK + lq * 8);
        #pragma unroll
        for (int j = 0; j < 4; ++j) b[j] = *(const half8*)(Bs + (wn + j * 16 + lr) * BK + lq * 8);
        #pragma unroll
        for (int i = 0; i < 4; ++i)
            #pragma unroll
            for (int j = 0; j < 4; ++j)
                acc[i][j] = __builtin_amdgcn_mfma_f32_16x16x32_f16(a[i], b[j], acc[i][j], 0, 0, 0);
        __syncthreads();
    }

    // C/D layout: col = lane&15, row = (lane>>4)*4 + reg
    #pragma unroll
    for (int i = 0; i < 4; ++i)
        #pragma unroll
        for (int j = 0; j < 4; ++j)
            #pragma unroll
            for (int r = 0; r < 4; ++r) {
                long row = m0 + wm + i * 16 + lq * 4 + r;
                long col = n0 + wn + j * 16 + lr;
                float v = alpha * acc[i][j][r];
                if (Ch) {
                    long cm = cmap ? ((col >> 6) * 128 + (col & 63)) : col;
                    Ch[cofs + row * ldch + cm] = (_Float16)v;
                }
                if (Cf && col >= cf_lo && col < cf_hi)
                    Cf[cofs + row * ldcf + (col - cf_lo)] = v;
            }
}

__global__ void cast_f16_kernel(const float* __restrict__ in, _Float16* __restrict__ out, int n)
{
    int i = blockIdx.x * 256 + threadIdx.x;
    if (i < n) out[i] = (_Float16)in[i];
}

// batched transpose: out_z[c][r] = (f16) in_z[r][c], z selects pointer pair
__global__ void trx_kernel(const float* __restrict__ in0, const float* __restrict__ in1,
                           const float* __restrict__ in2,
                           _Float16* __restrict__ o0, _Float16* __restrict__ o1,
                           _Float16* __restrict__ o2, int R, int C)
{
    const float* in = blockIdx.z == 0 ? in0 : (blockIdx.z == 1 ? in1 : in2);
    _Float16* out = blockIdx.z == 0 ? o0 : (blockIdx.z == 1 ? o1 : o2);
    __shared__ float tbuf[32][33];
    int c0 = blockIdx.x * 32, r0 = blockIdx.y * 32;
    for (int i = threadIdx.y; i < 32; i += 8)
        tbuf[i][threadIdx.x] = in[(long)(r0 + i) * C + c0 + threadIdx.x];
    __syncthreads();
    for (int i = threadIdx.y; i < 32; i += 8)
        out[(long)(c0 + i) * R + r0 + threadIdx.x] = (_Float16)tbuf[threadIdx.x][i];
}

// rope on k_r (f16, cols 2048..3071 of catA [4096][3072]); writes fp32 output 2
// and the rope half of k_flat (f16, [4096][h*128+64+d]).
__global__ void rope_k_kernel(const _Float16* __restrict__ catA,
                              float* __restrict__ krope_out,
                              _Float16* __restrict__ k_flat)
{
    int idx = blockIdx.x * 256 + threadIdx.x;   // 4096*1024
    int bs = idx >> 10;
    int c = idx & 1023;
    int h = c >> 6, d = c & 63;
    long base = (long)bs * 3072 + 2048;
    float x = (float)catA[base + c];
    float y = x;
    if (d < 32) {
        int s = bs & 2047;
        int j = d & 15;
        float invf = powf(10000.0f, -(float)j / 16.0f);
        float ang = ((float)s / 40.0f) * invf;
        float other = (d < 16) ? -(float)catA[base + c + 16] : (float)catA[base + c - 16];
        y = x * cosf(ang) + other * sinf(ang);
    }
    krope_out[idx] = y;
    k_flat[(long)bs * 2048 + h * 128 + 64 + d] = (_Float16)y;
}

// build qT [2048 dims][4096 seq] f16 from q_crT (f16 [2048][4096]: rows 0-1023 q_c, 1024-2047 q_r)
__global__ void rope_qT_kernel(const _Float16* __restrict__ q_crT,
                               _Float16* __restrict__ qT)
{
    long idx = (long)blockIdx.x * 256 + threadIdx.x;   // 2048*4096
    int row = (int)(idx >> 12);
    int col = (int)(idx & 4095);
    int h = row >> 7, d = row & 127;
    if (d < 64) {
        qT[idx] = q_crT[(long)(h * 64 + d) * 4096 + col];
    } else {
        int dd = d - 64;
        long base = (long)(1024 + h * 64) * 4096 + col;
        float x = (float)q_crT[base + (long)dd * 4096];
        float y = x;
        if (dd < 32) {
            int s = col & 2047;
            int j = dd & 15;
            float invf = powf(10000.0f, -(float)j / 16.0f);
            float ang = ((float)s / 40.0f) * invf;
            float other = (dd < 16) ? -(float)q_crT[base + (long)(dd + 16) * 4096]
                                    :  (float)q_crT[base + (long)(dd - 16) * 4096];
            y = x * cosf(ang) + other * sinf(ang);
        }
        qT[idx] = (_Float16)y;
    }
}

// Mbuf16[i] = (f16) sum_{j<8} Mp[j*524288 + i]
__global__ void reduce8_cast_kernel(const float* __restrict__ in, _Float16* __restrict__ out)
{
    int i = blockIdx.x * 256 + threadIdx.x;   // 524288
    float s = 0.f;
    #pragma unroll
    for (int j = 0; j < 8; ++j) s += in[i + j * 524288];
    out[i] = (_Float16)s;
}

extern "C" void kernel_launch(void* const* d_in, const int* in_sizes, int n_in,
                              void* d_out, int out_size, void* d_ws, size_t ws_size,
                              hipStream_t stream)
{
    const float* x     = (const float*)d_in[0];
    const float* W_dkv = (const float*)d_in[1];
    const float* W_dq  = (const float*)d_in[2];
    const float* W_uk  = (const float*)d_in[3];
    const float* W_uv  = (const float*)d_in[4];
    const float* W_uq  = (const float*)d_in[5];
    const float* W_kr  = (const float*)d_in[6];
    const float* W_qr  = (const float*)d_in[7];
    const float* W_out = (const float*)d_in[8];

    float* out_main  = (float*)d_out;            // [2][2048][2048]
    float* out_ckv   = out_main + 8388608;       // [2][2048][1024]
    float* out_krope = out_ckv + 4194304;        // [2][2048][16][64]

    char* w = (char*)d_ws;
    size_t off = 0;
    auto alloc = [&](size_t bytes) { void* p = w + off; off += (bytes + 255) & ~(size_t)255; return p; };

    _Float16* catA    = (_Float16*)alloc(25165824);  // [4096][3072]: c_kv | c_q | k_r
    _Float16* WcatT   = (_Float16*)alloc(12582912);  // [3072][2048]: WdkvT|WdqT|WkrT
    _Float16* WukT    = (_Float16*)alloc(2097152);   // also Mbuf16 (1MB) after G5
    _Float16* WuqcatT = (_Float16*)alloc(4194304);   // rows 0-1023 WuqT, 1024-2047 WuqrT
    _Float16* WqrT    = (_Float16*)alloc(2097152);
    _Float16* Wuqh    = (_Float16*)alloc(2097152);
    _Float16* WuvT    = (_Float16*)alloc(4194304);   // [2048][1024]
    _Float16* WoutT   = (_Float16*)alloc(8388608);   // [2048][2048]
    void* reg_xq      = alloc(16777216);             // xh [4096][2048] -> qT [2048][4096]
    _Float16* k_flat  = (_Float16*)alloc(16777216);  // [4096][2048]
    _Float16* vT      = (_Float16*)alloc(16777216);  // [2048][4096]
    void* reg_qp      = alloc(16777216);             // q_crT -> Mbuf32p (8 slices fp32) -> PT

    _Float16* xh     = (_Float16*)reg_xq;
    _Float16* qT     = (_Float16*)reg_xq;
    _Float16* q_crT  = (_Float16*)reg_qp;
    float*    Mbuf32p = (float*)reg_qp;              // [8][32*128*128] fp32 = 16.8 MB
    _Float16* PT     = (_Float16*)reg_qp;            // [2][2048][2048]
    _Float16* WuqT   = WuqcatT;
    _Float16* WuqrT  = WuqcatT + 1048576;
    _Float16* Mbuf16 = WukT;                          // 1 MB, after G5 done with WukT

    #define GF(A_,B_,Cf_,Ch_,M_,N_,Kc_,lda_,ldb_,ldcf_,ldch_,cmap_,cflo_,cfhi_,alpha_,nb_,nh_,nsk_,ab,ah,bb,bh,cb,ch2,cs) \
        hipLaunchKernelGGL(gemm_fast, dim3((N_)/128,(M_)/128,(nb_)*(nh_)*(nsk_)), dim3(256), 0, stream, \
            A_, B_, Cf_, Ch_, (int)(Kc_), (long)(lda_), (long)(ldb_), (long)(ldcf_), (long)(ldch_), \
            cmap_, (long)(cflo_), (long)(cfhi_), (float)(alpha_), nh_, nsk_, \
            (long)(ab),(long)(ah),(long)(bb),(long)(bh),(long)(cb),(long)(ch2),(long)(cs))

    // --- prep ---
    hipLaunchKernelGGL(cast_f16_kernel, dim3(32768), dim3(256), 0, stream, x, xh, 8388608);
    hipLaunchKernelGGL(cast_f16_kernel, dim3(4096), dim3(256), 0, stream, W_uq, Wuqh, 1048576);
    hipLaunchKernelGGL(trx_kernel, dim3(32, 64, 3), dim3(32, 8), 0, stream,
        W_dkv, W_dq, W_kr, WcatT, WcatT + 2097152, WcatT + 4194304, 2048, 1024);
    hipLaunchKernelGGL(trx_kernel, dim3(32, 32, 3), dim3(32, 8), 0, stream,
        W_uk, W_uq, W_qr, WukT, WuqT, WqrT, 1024, 1024);
    hipLaunchKernelGGL(trx_kernel, dim3(64, 32, 1), dim3(32, 8), 0, stream,
        W_uv, W_uv, W_uv, WuvT, WuvT, WuvT, 1024, 2048);
    hipLaunchKernelGGL(trx_kernel, dim3(64, 64, 1), dim3(32, 8), 0, stream,
        W_out, W_out, W_out, WoutT, WoutT, WoutT, 2048, 2048);

    // G123: [c_kv|c_q|k_r] = x @ [W_dkv|W_dq|W_kr]; f16 catA + fp32 out_ckv (cols 0-1023)
    GF(xh, WcatT, out_ckv, catA, 4096, 3072, 2048, 2048, 2048, 1024, 3072, 0, 0, 1024, 1.0,
       1, 1, 1, 0,0,0,0,0,0,0);
    // G4: WuqrT[r][cd] = WqrT @ Wuqh
    GF(WqrT, Wuqh, (float*)nullptr, WuqrT, 1024, 1024, 1024, 1024, 1024, 0, 1024, 0, 0, 0, 1.0,
       1, 1, 1, 0,0,0,0,0,0,0);
    // G5: k_c -> content cols of k_flat (remap h*64+d -> h*128+d)
    GF(catA, WukT, (float*)nullptr, k_flat, 4096, 1024, 1024, 3072, 1024, 0, 2048, 1, 0, 0, 1.0,
       1, 1, 1, 0,0,0,0,0,0,0);
    // G6: vT[h*128+dv][seq] = WuvT @ c_kv
    GF(WuvT, catA, (float*)nullptr, vT, 2048, 4096, 1024, 1024, 3072, 0, 4096, 0, 0, 0, 1.0,
       1, 1, 1, 0,0,0,0,0,0,0);
    // G78: q_crT[2048][4096] = [WuqT; WuqrT] @ c_q
    GF(WuqcatT, catA + 1024, (float*)nullptr, q_crT, 2048, 4096, 1024, 1024, 3072, 0, 4096, 0, 0, 0, 1.0,
       1, 1, 1, 0,0,0,0,0,0,0);
    // rope
    hipLaunchKernelGGL(rope_k_kernel, dim3(16384), dim3(256), 0, stream, catA, out_krope, k_flat);
    hipLaunchKernelGGL(rope_qT_kernel, dim3(32768), dim3(256), 0, stream, q_crT, qT);
    // G9: M partials (split-K 8): Mp[ks][b,h][dk][dv] = (1/sqrt128) qT_h @ vT_h^T chunk
    // coff_s = 524288 ELEMENTS (slice stride; 8 x 524288 floats fills reg_qp exactly)
    GF(qT, vT, Mbuf32p, (_Float16*)nullptr, 128, 128, 256, 4096, 4096, 128, 0, 0, 0, 128,
       0.08838834764831845, 2, 16, 8, 2048, 524288, 2048, 524288, 262144, 16384, 524288);
    hipLaunchKernelGGL(reduce8_cast_kernel, dim3(2048), dim3(256), 0, stream, Mbuf32p, Mbuf16);
    // G10: PT[b][o][h*128+dk] = WoutT_h @ M_h^T
    GF(WoutT, Mbuf16, (float*)nullptr, PT, 2048, 128, 128, 2048, 128, 0, 2048, 0, 0, 0, 1.0,
       2, 16, 1, 0, 128, 262144, 16384, 4194304, 128, 0);
    // G11: output[b] = k_flat[b] @ PT[b]^T (fp32 output 0)
    GF(k_flat, PT, out_main, (_Float16*)nullptr, 2048, 2048, 2048, 2048, 2048, 2048, 0, 0, 0, 2048, 1.0,
       2, 1, 1, 4194304, 0, 4194304, 0, 4194304, 0, 0);

    #undef GF
}

// Round 5
// 474.815 us; speedup vs baseline: 2.3777x; 1.0619x over previous
//
#include <hip/hip_runtime.h>
#include <math.h>

typedef _Float16 half8 __attribute__((ext_vector_type(8)));
typedef float floatx4 __attribute__((ext_vector_type(4)));

typedef const uint32_t __attribute__((address_space(1)))* gp1_t;
typedef uint32_t __attribute__((address_space(3)))* lp3_t;
#define GLDS16(g, l) __builtin_amdgcn_global_load_lds((gp1_t)(const void*)(g), (lp3_t)(void*)(l), 16, 0, 0)

#define BK 32

// C[m][n] = alpha * sum_k A[m][k]*B[n][k]; A,B f16 k-contiguous; 128x128 tile, m97 structure.
// epi_mode 0: optional f16 Ch (cmap head-interleave) + optional fp32 Cf col-window [cf_lo,cf_hi)
// epi_mode 1 (G123): cols<1024 -> Ch(catA)+Cf(c_kv fp32); 1024..2047 -> Ch(catA);
//                    >=2048 -> in-register rope-k -> Cx(krope fp32) + Cy(k_flat f16 rope half)
// epi_mode 2 (G6/G78 merged): zb==0 plain Ch (vT); zb==1 qT assembly (+rope on q_r rows)
__global__ __launch_bounds__(256) void gemm_fast(
    const _Float16* __restrict__ A, const _Float16* __restrict__ B,
    float* __restrict__ Cf, _Float16* __restrict__ Ch,
    float* __restrict__ Cx, _Float16* __restrict__ Cy,
    int Kc, long lda, long ldb, long ldcf, long ldch,
    int cmap, long cf_lo, long cf_hi, float alpha, int nh, int nsk, int epi_mode,
    long aoff_b, long aoff_h, long boff_b, long boff_h,
    long coff_b, long coff_h, long coff_s)
{
    __shared__ __align__(16) _Float16 As[128 * BK];
    __shared__ __align__(16) _Float16 Bs[128 * BK];

    const int z = blockIdx.z;
    const int hs = nh * nsk;
    const int zb = z / hs;
    const int rr = z % hs;
    const int zh = rr / nsk;
    const int ks = rr % nsk;

    const _Float16* Ab = A + (long)zb * aoff_b + (long)zh * aoff_h + (long)ks * Kc;
    const _Float16* Bb = B + (long)zb * boff_b + (long)zh * boff_h + (long)ks * Kc;
    const long cofs = (long)zb * coff_b + (long)zh * coff_h + (long)ks * coff_s;

    const long m0 = (long)blockIdx.y * 128;
    const long n0 = (long)blockIdx.x * 128;
    const int t = threadIdx.x;
    const int wave = t >> 6, lane = t & 63;
    const int lr = lane & 15, lq = lane >> 4;
    const int wm = (wave & 1) * 64, wn = (wave >> 1) * 64;

    const int c0 = wave * 64 + lane;
    const int c1 = c0 + 256;
    const _Float16* ga0 = Ab + (m0 + (c0 >> 2)) * lda + (c0 & 3) * 8;
    const _Float16* ga1 = Ab + (m0 + (c1 >> 2)) * lda + (c1 & 3) * 8;
    const _Float16* gb0 = Bb + (n0 + (c0 >> 2)) * ldb + (c0 & 3) * 8;
    const _Float16* gb1 = Bb + (n0 + (c1 >> 2)) * ldb + (c1 & 3) * 8;
    _Float16* lA0 = As + wave * 512;
    _Float16* lA1 = As + 2048 + wave * 512;
    _Float16* lB0 = Bs + wave * 512;
    _Float16* lB1 = Bs + 2048 + wave * 512;

    floatx4 acc[4][4];
    #pragma unroll
    for (int i = 0; i < 4; ++i)
        #pragma unroll
        for (int j = 0; j < 4; ++j) acc[i][j] = (floatx4){0.f, 0.f, 0.f, 0.f};

    for (int k0 = 0; k0 < Kc; k0 += BK) {
        GLDS16(ga0, lA0); GLDS16(ga1, lA1);
        GLDS16(gb0, lB0); GLDS16(gb1, lB1);
        ga0 += BK; ga1 += BK; gb0 += BK; gb1 += BK;
        __syncthreads();

        half8 a[4], b[4];
        #pragma unroll
        for (int i = 0; i < 4; ++i) a[i] = *(const half8*)(As + (wm + i * 16 + lr) * BK + lq * 8);
        #pragma unroll
        for (int j = 0; j < 4; ++j) b[j] = *(const half8*)(Bs + (wn + j * 16 + lr) * BK + lq * 8);
        #pragma unroll
        for (int i = 0; i < 4; ++i)
            #pragma unroll
            for (int j = 0; j < 4; ++j)
                acc[i][j] = __builtin_amdgcn_mfma_f32_16x16x32_f16(a[i], b[j], acc[i][j], 0, 0, 0);
        __syncthreads();
    }

    // C/D layout: col = lane&15, row = (lane>>4)*4 + reg
    if (epi_mode == 0) {
        #pragma unroll
        for (int i = 0; i < 4; ++i)
            #pragma unroll
            for (int j = 0; j < 4; ++j)
                #pragma unroll
                for (int r = 0; r < 4; ++r) {
                    long row = m0 + wm + i * 16 + lq * 4 + r;
                    long col = n0 + wn + j * 16 + lr;
                    float v = alpha * acc[i][j][r];
                    if (Ch) {
                        long cm = cmap ? ((col >> 6) * 128 + (col & 63)) : col;
                        Ch[cofs + row * ldch + cm] = (_Float16)v;
                    }
                    if (Cf && col >= cf_lo && col < cf_hi)
                        Cf[cofs + row * ldcf + (col - cf_lo)] = v;
                }
    } else if (epi_mode == 1) {
        const int nb = (int)n0 + wn;   // wave col base, uniform
        if (nb < 2048) {
            #pragma unroll
            for (int i = 0; i < 4; ++i)
                #pragma unroll
                for (int j = 0; j < 4; ++j)
                    #pragma unroll
                    for (int r = 0; r < 4; ++r) {
                        long row = m0 + wm + i * 16 + lq * 4 + r;
                        long col = n0 + wn + j * 16 + lr;
                        float v = acc[i][j][r];
                        Ch[row * 2048 + col] = (_Float16)v;      // catA (c_kv|c_q)
                        if (nb < 1024) Cf[row * 1024 + col] = v; // c_kv fp32 output
                    }
        } else {
            const int h = (nb - 2048) >> 6;   // head, uniform per wave
            const float invf = powf(10000.0f, -(float)lr / 16.0f);
            #pragma unroll
            for (int i = 0; i < 4; ++i)
                #pragma unroll
                for (int r = 0; r < 4; ++r) {
                    long row = m0 + wm + i * 16 + lq * 4 + r;
                    int s = (int)row & 2047;
                    float ang = ((float)s / 40.0f) * invf;
                    float cv = cosf(ang), sv = sinf(ang);
                    float v0 = acc[i][0][r], v1 = acc[i][1][r];
                    float y[4] = { v0 * cv - v1 * sv, v1 * cv + v0 * sv,
                                   acc[i][2][r], acc[i][3][r] };
                    #pragma unroll
                    for (int j = 0; j < 4; ++j) {
                        int d = j * 16 + lr;
                        Cx[row * 1024 + h * 64 + d] = y[j];                   // krope fp32
                        Cy[row * 2048 + h * 128 + 64 + d] = (_Float16)y[j];   // k_flat rope half
                    }
                }
        }
    } else {  // epi_mode == 2
        if (zb == 0) {
            #pragma unroll
            for (int i = 0; i < 4; ++i)
                #pragma unroll
                for (int j = 0; j < 4; ++j)
                    #pragma unroll
                    for (int r = 0; r < 4; ++r) {
                        long row = m0 + wm + i * 16 + lq * 4 + r;
                        long col = n0 + wn + j * 16 + lr;
                        Ch[cofs + row * ldch + col] = (_Float16)acc[i][j][r];  // vT
                    }
        } else {
            const int mb = (int)m0 + wm;   // wave row base, uniform
            if (mb < 1024) {
                // q_c rows: qT row = (u>>6)*128 + (u&63)
                #pragma unroll
                for (int i = 0; i < 4; ++i)
                    #pragma unroll
                    for (int j = 0; j < 4; ++j)
                        #pragma unroll
                        for (int r = 0; r < 4; ++r) {
                            long u = m0 + wm + i * 16 + lq * 4 + r;
                            long col = n0 + wn + j * 16 + lr;
                            long qrow = ((u >> 6) << 7) + (u & 63);
                            Ch[cofs + qrow * 4096 + col] = (_Float16)acc[i][j][r];
                        }
            } else {
                const int h = (mb - 1024) >> 6;   // head, uniform per wave
                const float invf = powf(10000.0f, -(float)(lq * 4) / 16.0f);  // refined per r below
                #pragma unroll
                for (int j = 0; j < 4; ++j)
                    #pragma unroll
                    for (int r = 0; r < 4; ++r) {
                        long col = n0 + wn + j * 16 + lr;
                        int s = (int)col & 2047;
                        int j16 = lq * 4 + r;
                        float ivf = powf(10000.0f, -(float)j16 / 16.0f);
                        float ang = ((float)s / 40.0f) * ivf;
                        float cv = cosf(ang), sv = sinf(ang);
                        float v0 = acc[0][j][r], v1 = acc[1][j][r];
                        float y[4] = { v0 * cv - v1 * sv, v1 * cv + v0 * sv,
                                       acc[2][j][r], acc[3][j][r] };
                        #pragma unroll
                        for (int i = 0; i < 4; ++i) {
                            int dd = i * 16 + lq * 4 + r;
                            long qrow = h * 128 + 64 + dd;
                            Ch[cofs + qrow * 4096 + col] = (_Float16)y[i];
                        }
                    }
                (void)invf;
            }
        }
    }
}

// ---- mega prep: 8 weight transposes (f32->f16 T) + 2 casts, one launch ----
__device__ inline void tr_tile(const float* __restrict__ in, _Float16* __restrict__ out,
                               int R, int C, int tile, int tx, int ty, float (*tb)[33])
{
    int tc = tile % (C >> 5), tr = tile / (C >> 5);
    int c0 = tc * 32, r0 = tr * 32;
    for (int i = ty; i < 32; i += 8)
        tb[i][tx] = in[(long)(r0 + i) * C + c0 + tx];
    __syncthreads();
    for (int i = ty; i < 32; i += 8)
        out[(long)(c0 + i) * R + r0 + tx] = (_Float16)tb[tx][i];
}

__device__ inline void cast_blk(const float* __restrict__ in, _Float16* __restrict__ out,
                                int blk, int tid)
{
    long idx = (long)blk * 2048 + tid * 8;
    float4 a = ((const float4*)(in + idx))[0];
    float4 b = ((const float4*)(in + idx))[1];
    half8 h = { (_Float16)a.x, (_Float16)a.y, (_Float16)a.z, (_Float16)a.w,
                (_Float16)b.x, (_Float16)b.y, (_Float16)b.z, (_Float16)b.w };
    *(half8*)(out + idx) = h;
}

__global__ void prep_kernel(
    const float* __restrict__ x, const float* __restrict__ W_dkv,
    const float* __restrict__ W_dq, const float* __restrict__ W_uk,
    const float* __restrict__ W_uv, const float* __restrict__ W_uq,
    const float* __restrict__ W_kr, const float* __restrict__ W_qr,
    const float* __restrict__ W_out,
    _Float16* __restrict__ WcatT, _Float16* __restrict__ WukT,
    _Float16* __restrict__ WuvT, _Float16* __restrict__ WuqcatT,
    _Float16* __restrict__ WqrT, _Float16* __restrict__ Wuqh,
    _Float16* __restrict__ WoutT, _Float16* __restrict__ xh)
{
    __shared__ float tb[32][33];
    int blk = blockIdx.x;
    int tid = threadIdx.x;
    int tx = tid & 31, ty = tid >> 5;
    if (blk < 2048)        tr_tile(W_dkv, WcatT,            2048, 1024, blk,         tx, ty, tb);
    else if (blk < 4096)   tr_tile(W_dq,  WcatT + 2097152,  2048, 1024, blk - 2048,  tx, ty, tb);
    else if (blk < 6144)   tr_tile(W_kr,  WcatT + 4194304,  2048, 1024, blk - 4096,  tx, ty, tb);
    else if (blk < 7168)   tr_tile(W_uk,  WukT,             1024, 1024, blk - 6144,  tx, ty, tb);
    else if (blk < 8192)   tr_tile(W_uq,  WuqcatT,          1024, 1024, blk - 7168,  tx, ty, tb);
    else if (blk < 9216)   tr_tile(W_qr,  WqrT,             1024, 1024, blk - 8192,  tx, ty, tb);
    else if (blk < 11264)  tr_tile(W_uv,  WuvT,             1024, 2048, blk - 9216,  tx, ty, tb);
    else if (blk < 15360)  tr_tile(W_out, WoutT,            2048, 2048, blk - 11264, tx, ty, tb);
    else if (blk < 19456)  cast_blk(x,    xh,   blk - 15360, tid);
    else                   cast_blk(W_uq, Wuqh, blk - 19456, tid);
}

// Mbuf16[i] = (f16) sum_{j<8} Mp[j*524288 + i]
__global__ void reduce8_cast_kernel(const float* __restrict__ in, _Float16* __restrict__ out)
{
    int i = blockIdx.x * 256 + threadIdx.x;   // 524288
    float s = 0.f;
    #pragma unroll
    for (int j = 0; j < 8; ++j) s += in[i + j * 524288];
    out[i] = (_Float16)s;
}

extern "C" void kernel_launch(void* const* d_in, const int* in_sizes, int n_in,
                              void* d_out, int out_size, void* d_ws, size_t ws_size,
                              hipStream_t stream)
{
    const float* x     = (const float*)d_in[0];
    const float* W_dkv = (const float*)d_in[1];
    const float* W_dq  = (const float*)d_in[2];
    const float* W_uk  = (const float*)d_in[3];
    const float* W_uv  = (const float*)d_in[4];
    const float* W_uq  = (const float*)d_in[5];
    const float* W_kr  = (const float*)d_in[6];
    const float* W_qr  = (const float*)d_in[7];
    const float* W_out = (const float*)d_in[8];

    float* out_main  = (float*)d_out;            // [2][2048][2048]
    float* out_ckv   = out_main + 8388608;       // [2][2048][1024]
    float* out_krope = out_ckv + 4194304;        // [2][2048][16][64]

    char* w = (char*)d_ws;
    size_t off = 0;
    auto alloc = [&](size_t bytes) { void* p = w + off; off += (bytes + 255) & ~(size_t)255; return p; };

    _Float16* catA    = (_Float16*)alloc(16777216);  // [4096][2048]: c_kv | c_q  (-> PT later)
    _Float16* WcatT   = (_Float16*)alloc(12582912);  // [3072][2048]: WdkvT|WdqT|WkrT
    _Float16* WukT    = (_Float16*)alloc(2097152);   // -> Mbuf16 after G5
    _Float16* WuvT    = (_Float16*)alloc(4194304);   // [2048][1024]   (adjacent to WuqcatT!)
    _Float16* WuqcatT = (_Float16*)alloc(4194304);   // rows 0-1023 WuqT, 1024-2047 WuqrT
    _Float16* WqrT    = (_Float16*)alloc(2097152);
    _Float16* Wuqh    = (_Float16*)alloc(2097152);
    _Float16* WoutT   = (_Float16*)alloc(8388608);   // [2048][2048]
    void*     reg_xm  = alloc(16777216);             // xh [4096][2048] -> Mbuf32p [8][524288] fp32
    _Float16* k_flat  = (_Float16*)alloc(16777216);  // [4096][2048]
    _Float16* vT      = (_Float16*)alloc(16777216);  // [2048][4096]   (adjacent to qT!)
    _Float16* qT      = (_Float16*)alloc(16777216);  // [2048][4096]

    _Float16* xh      = (_Float16*)reg_xm;
    float*    Mbuf32p = (float*)reg_xm;              // aliases xh (dead after G678)
    _Float16* PT      = catA;                        // aliases catA (dead after G678)
    _Float16* WuqrT   = WuqcatT + 1048576;
    _Float16* Mbuf16  = WukT;                        // aliases WukT (dead after G5)

    #define GF(A_,B_,Cf_,Ch_,Cx_,Cy_,M_,N_,Kc_,lda_,ldb_,ldcf_,ldch_,cmap_,cflo_,cfhi_,alpha_,nb_,nh_,nsk_,mode_,ab,ah,bb,bh,cb,ch2,cs) \
        hipLaunchKernelGGL(gemm_fast, dim3((N_)/128,(M_)/128,(nb_)*(nh_)*(nsk_)), dim3(256), 0, stream, \
            A_, B_, Cf_, Ch_, Cx_, Cy_, (int)(Kc_), (long)(lda_), (long)(ldb_), (long)(ldcf_), (long)(ldch_), \
            cmap_, (long)(cflo_), (long)(cfhi_), (float)(alpha_), nh_, nsk_, mode_, \
            (long)(ab),(long)(ah),(long)(bb),(long)(bh),(long)(cb),(long)(ch2),(long)(cs))

    // P0: mega prep (all transposes + casts), one launch
    hipLaunchKernelGGL(prep_kernel, dim3(19968), dim3(256), 0, stream,
        x, W_dkv, W_dq, W_uk, W_uv, W_uq, W_kr, W_qr, W_out,
        WcatT, WukT, WuvT, WuqcatT, WqrT, Wuqh, WoutT, xh);

    // G123 (mode 1): [c_kv|c_q|k_r] = x @ WcatT; writes catA f16 (cols<2048),
    // out_ckv fp32 (cols<1024), rope-k fused: out_krope fp32 + k_flat rope half (cols>=2048)
    GF(xh, WcatT, out_ckv, catA, out_krope, k_flat, 4096, 3072, 2048, 2048, 2048, 0, 0,
       0, 0, 0, 1.0, 1, 1, 1, 1, 0,0,0,0,0,0,0);
    // G4: WuqrT = WqrT @ Wuqh  [1024 r][1024 cd]
    GF(WqrT, Wuqh, (float*)nullptr, WuqrT, (float*)nullptr, (_Float16*)nullptr,
       1024, 1024, 1024, 1024, 1024, 0, 1024, 0, 0, 0, 1.0, 1, 1, 1, 0, 0,0,0,0,0,0,0);
    // G5: k_c content cols of k_flat (cmap h*64+d -> h*128+d); A = catA c_kv window
    GF(catA, WukT, (float*)nullptr, k_flat, (float*)nullptr, (_Float16*)nullptr,
       4096, 1024, 1024, 2048, 1024, 0, 2048, 1, 0, 0, 1.0, 1, 1, 1, 0, 0,0,0,0,0,0,0);
    // G678 (mode 2, z=2): z0 vT = WuvT @ c_kv^T; z1 qT assembly (+rope) = [WuqT;WuqrT] @ c_q^T
    GF(WuvT, catA, (float*)nullptr, vT, (float*)nullptr, (_Float16*)nullptr,
       2048, 4096, 1024, 1024, 2048, 0, 4096, 0, 0, 0, 1.0, 2, 1, 1, 2,
       2097152, 0, 1024, 0, 8388608, 0, 0);
    // G9: M partials (split-K 8): Mp[ks][b,h] = (1/sqrt128) qT_h @ vT_h^T chunk
    GF(qT, vT, Mbuf32p, (_Float16*)nullptr, (float*)nullptr, (_Float16*)nullptr,
       128, 128, 256, 4096, 4096, 128, 0, 0, 0, 128, 0.08838834764831845, 2, 16, 8, 0,
       2048, 524288, 2048, 524288, 262144, 16384, 524288);
    hipLaunchKernelGGL(reduce8_cast_kernel, dim3(2048), dim3(256), 0, stream, Mbuf32p, Mbuf16);
    // G10: PT[b][o][h*128+dk] = WoutT_h @ M_h^T
    GF(WoutT, Mbuf16, (float*)nullptr, PT, (float*)nullptr, (_Float16*)nullptr,
       2048, 128, 128, 2048, 128, 0, 2048, 0, 0, 0, 1.0, 2, 16, 1, 0,
       0, 128, 262144, 16384, 4194304, 128, 0);
    // G11: output[b] = k_flat[b] @ PT[b]^T (fp32 output 0)
    GF(k_flat, PT, out_main, (_Float16*)nullptr, (float*)nullptr, (_Float16*)nullptr,
       2048, 2048, 2048, 2048, 2048, 2048, 0, 0, 0, 2048, 1.0, 2, 1, 1, 0,
       4194304, 0, 4194304, 0, 4194304, 0, 0);

    #undef GF
}